// Round 2
// baseline (5679.572 us; speedup 1.0000x reference)
//
#include <hip/hip_runtime.h>

#define T_STEPS 1000
#define N_IN    700
#define N_HID   4096
#define N_OUT   20
#define NBLK    64
#define HPB     64   // N_HID / NBLK

// ---------------------------------------------------------------------------
// out[c*out_stride + r] = (int8) in[r*C + c]
__global__ __launch_bounds__(256) void k_transpose_i8(
    const int* __restrict__ in, signed char* __restrict__ out,
    int R, int C, int out_stride)
{
    __shared__ signed char tile[32][33];
    const int cx = blockIdx.x * 32;
    const int ry = blockIdx.y * 32;
    const int tx = threadIdx.x;   // 0..31
    const int ty = threadIdx.y;   // 0..7
#pragma unroll
    for (int r = 0; r < 4; ++r) {
        int row = ry + ty + r * 8;
        int col = cx + tx;
        if (row < R && col < C)
            tile[ty + r * 8][tx] = (signed char)in[(size_t)row * C + col];
    }
    __syncthreads();
#pragma unroll
    for (int r = 0; r < 4; ++r) {
        int c   = cx + ty + r * 8;
        int row = ry + tx;
        if (c < C && row < R)
            out[(size_t)c * out_stride + row] = tile[tx][ty + r * 8];
    }
}

// ---------------------------------------------------------------------------
// in_all[t][h] = sum_i w1t[i][h] * spk[t][i]   (|result| <= 5600 -> int16)
__global__ __launch_bounds__(256) void k_inall(
    const signed char* __restrict__ w1t,   // [N_IN][N_HID]
    const int* __restrict__ spk,           // [T][N_IN], values 0/1
    short* __restrict__ in_all)            // [T][N_HID]
{
    __shared__ int s_spk[16][N_IN];
    const int t0 = blockIdx.y * 16;
    const int tcnt = min(16, T_STEPS - t0);
    const int tid = threadIdx.x;
    for (int b = 0; b < tcnt; ++b)
        for (int i = tid; i < N_IN; i += 256)
            s_spk[b][i] = spk[(size_t)(t0 + b) * N_IN + i];
    __syncthreads();
    const int h = blockIdx.x * 256 + tid;
    int acc[16];
#pragma unroll
    for (int b = 0; b < 16; ++b) acc[b] = 0;
    for (int i = 0; i < N_IN; ++i) {
        int w = (int)w1t[(size_t)i * N_HID + h];
#pragma unroll
        for (int b = 0; b < 16; ++b) acc[b] += w * s_spk[b][i];
    }
    for (int b = 0; b < tcnt; ++b)
        in_all[(size_t)(t0 + b) * N_HID + h] = (short)acc[b];
}

// ---------------------------------------------------------------------------
// Main sequential LIF loop. 64 blocks x 256 threads, plain launch (all
// blocks trivially co-resident on 256 CUs). Grid-wide sync via a per-step
// arrival counter in d_ws (device-scope atomics -> XCD-coherent).
// Block b owns neurons [b*64, b*64+64). Spikes exchanged via per-step
// index lists (order-independent sums -> deterministic output).
__global__ __launch_bounds__(256) void k_main(
    const short* __restrict__ in_all,      // [T][N_HID]
    const signed char* __restrict__ v1t,   // [N_HID(k)][N_HID(h)]
    unsigned short* __restrict__ lists,    // [T][N_HID]
    int* __restrict__ counts,              // [T], pre-zeroed
    int* __restrict__ bar)                 // [T], pre-zeroed
{
    const int tid  = threadIdx.x;
    const int wave = tid >> 6;   // 0..3
    const int lane = tid & 63;
    const int hb   = blockIdx.x * HPB;

    __shared__ unsigned short s_list[N_HID];
    __shared__ int4 s_part[4][16];
    __shared__ int  s_fb[HPB];
    __shared__ int  s_n;

    // LIF state: wave 0, lane l <-> neuron hb+l
    int mem = 0, syn = 0, prev_out = 0;

    for (int t = 0; t < T_STEPS; ++t) {
        // ---- stage previous step's spike list ----
        int n = 0;
        if (t > 0) {
            if (tid == 0) s_n = counts[t - 1];
            __syncthreads();
            n = s_n;
            const unsigned short* lp = lists + (size_t)(t - 1) * N_HID;
            for (int j = tid; j < n; j += 256) s_list[j] = lp[j];
            __syncthreads();
        }

        // ---- feedback gather: fb[h] = sum_{k in spikes} v1t[k][h] ----
        // lane group g handles k-subset (wave*4+g) mod 16; char4 per lane.
        int4 acc = {0, 0, 0, 0};
        {
            const int g  = lane >> 4;          // 0..3
            const int li = lane & 15;          // 0..15
            const int wg = (wave << 2) | g;    // 0..15
            const signed char* base = v1t + hb + (li << 2);
#pragma unroll 16
            for (int j = wg; j < n; j += 16) {
                int k = s_list[j];
                int v = *(const int*)(base + (k << 12));
                acc.x += (v << 24) >> 24;
                acc.y += (v << 16) >> 24;
                acc.z += (v << 8)  >> 24;
                acc.w +=  v        >> 24;
            }
        }
        // reduce across the 4 lane groups (lanes l, l^16, l^32, l^48)
#pragma unroll
        for (int m = 16; m <= 32; m <<= 1) {
            acc.x += __shfl_xor(acc.x, m);
            acc.y += __shfl_xor(acc.y, m);
            acc.z += __shfl_xor(acc.z, m);
            acc.w += __shfl_xor(acc.w, m);
        }
        if (lane < 16) s_part[wave][lane] = acc;
        __syncthreads();

        if (wave == 0 && lane < 16) {
            int4 r;
            r.x = s_part[0][lane].x + s_part[1][lane].x + s_part[2][lane].x + s_part[3][lane].x;
            r.y = s_part[0][lane].y + s_part[1][lane].y + s_part[2][lane].y + s_part[3][lane].y;
            r.z = s_part[0][lane].z + s_part[1][lane].z + s_part[2][lane].z + s_part[3][lane].z;
            r.w = s_part[0][lane].w + s_part[1][lane].w + s_part[2][lane].w + s_part[3][lane].w;
            s_fb[(lane << 2) + 0] = r.x;
            s_fb[(lane << 2) + 1] = r.y;
            s_fb[(lane << 2) + 2] = r.z;
            s_fb[(lane << 2) + 3] = r.w;
        }
        __syncthreads();

        // ---- LIF update + spike publish (wave 0) ----
        if (wave == 0) {
            int fb = s_fb[lane];
            int syn_curr = (int)in_all[(size_t)t * N_HID + hb + lane] + fb;
            int m  = prev_out ? 0 : mem;             // reset by previous spike
            int out = (m - 1 > 0) ? 1 : 0;           // threshold on reset mem
            mem = (m - (m >> 3)) + syn;              // beta decay + old syn
            syn = (syn - (syn >> 4)) + syn_curr;     // alpha decay + current
            prev_out = out;

            unsigned long long mask = __ballot(out);
            int cnt = __popcll(mask);
            int pos = 0;
            if (lane == 0 && cnt > 0) pos = atomicAdd(&counts[t], cnt);
            pos = __shfl(pos, 0);
            if (out) {
                int rank = __popcll(mask & ((1ull << lane) - 1ull));
                lists[(size_t)t * N_HID + pos + rank] = (unsigned short)(hb + lane);
            }
        }

        // ---- grid-wide barrier (device-scope, graph-capture safe) ----
        __syncthreads();                     // all block writes done
        if (tid == 0) {
            __threadfence();                 // release block's global writes
            __hip_atomic_fetch_add(&bar[t], 1, __ATOMIC_RELEASE,
                                   __HIP_MEMORY_SCOPE_AGENT);
            while (__hip_atomic_load(&bar[t], __ATOMIC_ACQUIRE,
                                     __HIP_MEMORY_SCOPE_AGENT) < NBLK)
                __builtin_amdgcn_s_sleep(1);
        }
        __syncthreads();                     // fan visibility out to block
    }
}

// ---------------------------------------------------------------------------
// ro[t][o] = sum_{k in spikes(t)} w2[o][k]
__global__ __launch_bounds__(256) void k_rocur(
    const int* __restrict__ w2,                // [N_OUT][N_HID]
    const unsigned short* __restrict__ lists,
    const int* __restrict__ counts,
    int* __restrict__ ro)                      // [T][N_OUT]
{
    const int t = blockIdx.x;
    const int tid = threadIdx.x;
    __shared__ unsigned short s_list[N_HID];
    __shared__ int s_red[N_OUT][8];
    const int n = counts[t];
    const unsigned short* lp = lists + (size_t)t * N_HID;
    for (int j = tid; j < n; j += 256) s_list[j] = lp[j];
    __syncthreads();
    const int o = tid >> 3;
    const int r = tid & 7;
    if (o < N_OUT) {
        int acc = 0;
        for (int j = r; j < n; j += 8) acc += w2[(size_t)o * N_HID + s_list[j]];
        s_red[o][r] = acc;
    }
    __syncthreads();
    if (tid < N_OUT) {
        int acc = 0;
#pragma unroll
        for (int q = 0; q < 8; ++q) acc += s_red[tid][q];
        ro[(size_t)t * N_OUT + tid] = acc;
    }
}

// ---------------------------------------------------------------------------
// readout LIF scan (no reset), records updated membrane; out is [N_OUT][T],
// written as int32 (harness reads integer outputs as int32).
__global__ void k_scan(const int* __restrict__ ro, int* __restrict__ out)
{
    const int o = threadIdx.x;
    if (o >= N_OUT) return;
    int rm = 0, rs = 0;
    for (int t = 0; t < T_STEPS; ++t) {
        rm = (rm - (rm >> 3)) + rs;
        rs = (rs - (rs >> 4)) + ro[t * N_OUT + o];
        out[o * T_STEPS + t] = rm;
    }
}

// ---------------------------------------------------------------------------
extern "C" void kernel_launch(void* const* d_in, const int* in_sizes, int n_in,
                              void* d_out, int out_size, void* d_ws, size_t ws_size,
                              hipStream_t stream)
{
    const int* spk = (const int*)d_in[0];   // [1000][700]
    const int* w1  = (const int*)d_in[1];   // [4096][700]
    const int* v1  = (const int*)d_in[2];   // [4096][4096]
    const int* w2  = (const int*)d_in[3];   // [20][4096]
    int* out = (int*)d_out;                 // [20][1000] int32

    char* ws = (char*)d_ws;
    constexpr size_t OFF_INALL = 0;                        // 8,192,000 B
    constexpr size_t OFF_V1T   = 8192000;                  // 16,777,216 B
    constexpr size_t OFF_W1T   = OFF_V1T + 16777216;       // 2,867,200 B
    constexpr size_t OFF_LISTS = OFF_W1T + 2867200;        // 8,192,000 B
    constexpr size_t OFF_CNT   = OFF_LISTS + 8192000;      // 4,096 B
    constexpr size_t OFF_BAR   = OFF_CNT + 4096;           // 4,096 B
    constexpr size_t OFF_RO    = OFF_BAR + 4096;           // 80,000 B

    short*          in_all = (short*)(ws + OFF_INALL);
    signed char*    v1t    = (signed char*)(ws + OFF_V1T);
    signed char*    w1t    = (signed char*)(ws + OFF_W1T);
    unsigned short* lists  = (unsigned short*)(ws + OFF_LISTS);
    int*            counts = (int*)(ws + OFF_CNT);
    int*            bar    = (int*)(ws + OFF_BAR);
    int*            ro     = (int*)(ws + OFF_RO);

    // zero counts + barrier counters (adjacent, one memset)
    hipMemsetAsync(counts, 0, 8192, stream);

    dim3 tb(32, 8);
    k_transpose_i8<<<dim3(128, 128), tb, 0, stream>>>(v1, v1t, N_HID, N_HID, N_HID);
    k_transpose_i8<<<dim3(22, 128),  tb, 0, stream>>>(w1, w1t, N_HID, N_IN, N_HID);
    k_inall<<<dim3(16, 63), 256, 0, stream>>>(w1t, spk, in_all);

    k_main<<<dim3(NBLK), dim3(256), 0, stream>>>(in_all, v1t, lists, counts, bar);

    k_rocur<<<dim3(T_STEPS), 256, 0, stream>>>(w2, lists, counts, ro);
    k_scan<<<1, 32, 0, stream>>>(ro, out);
}

// Round 3
// 3921.547 us; speedup vs baseline: 1.4483x; 1.4483x over previous
//
#include <hip/hip_runtime.h>

#define T_STEPS 1000
#define N_IN    700
#define N_HID   4096
#define N_OUT   20
#define NBLK    64
#define HPB     64   // N_HID / NBLK

// ---------------------------------------------------------------------------
// out[c*out_stride + r] = (int8) in[r*C + c]
__global__ __launch_bounds__(256) void k_transpose_i8(
    const int* __restrict__ in, signed char* __restrict__ out,
    int R, int C, int out_stride)
{
    __shared__ signed char tile[32][33];
    const int cx = blockIdx.x * 32;
    const int ry = blockIdx.y * 32;
    const int tx = threadIdx.x;   // 0..31
    const int ty = threadIdx.y;   // 0..7
#pragma unroll
    for (int r = 0; r < 4; ++r) {
        int row = ry + ty + r * 8;
        int col = cx + tx;
        if (row < R && col < C)
            tile[ty + r * 8][tx] = (signed char)in[(size_t)row * C + col];
    }
    __syncthreads();
#pragma unroll
    for (int r = 0; r < 4; ++r) {
        int c   = cx + ty + r * 8;
        int row = ry + tx;
        if (c < C && row < R)
            out[(size_t)c * out_stride + row] = tile[tx][ty + r * 8];
    }
}

// ---------------------------------------------------------------------------
// in_all[t][h] = sum_i w1t[i][h] * spk[t][i]   (|result| <= 5600 -> int16)
__global__ __launch_bounds__(256) void k_inall(
    const signed char* __restrict__ w1t,   // [N_IN][N_HID]
    const int* __restrict__ spk,           // [T][N_IN], values 0/1
    short* __restrict__ in_all)            // [T][N_HID]
{
    __shared__ int s_spk[16][N_IN];
    const int t0 = blockIdx.y * 16;
    const int tcnt = min(16, T_STEPS - t0);
    const int tid = threadIdx.x;
    for (int b = 0; b < tcnt; ++b)
        for (int i = tid; i < N_IN; i += 256)
            s_spk[b][i] = spk[(size_t)(t0 + b) * N_IN + i];
    __syncthreads();
    const int h = blockIdx.x * 256 + tid;
    int acc[16];
#pragma unroll
    for (int b = 0; b < 16; ++b) acc[b] = 0;
    for (int i = 0; i < N_IN; ++i) {
        int w = (int)w1t[(size_t)i * N_HID + h];
#pragma unroll
        for (int b = 0; b < 16; ++b) acc[b] += w * s_spk[b][i];
    }
    for (int b = 0; b < tcnt; ++b)
        in_all[(size_t)(t0 + b) * N_HID + h] = (short)acc[b];
}

// ---------------------------------------------------------------------------
// Main sequential LIF loop. 64 blocks x 256 threads, plain launch (64 blocks
// on 256 CUs: trivially co-resident). NO explicit barrier: per-step spike
// masks are published as {lo, hi, flag} records (release), and each block's
// wave 0 acquire-polls all 64 flags of step t-1 — the exchange IS the sync.
// pub slots are write-once per (t, block), so block skew is harmless.
__global__ __launch_bounds__(256) void k_main(
    const short* __restrict__ in_all,      // [T][N_HID]
    const signed char* __restrict__ v1t,   // [N_HID(k)][N_HID(h)]
    uint4* __restrict__ pub)               // [T][NBLK] {lo, hi, flag, -}, zeroed
{
    const int tid  = threadIdx.x;
    const int wave = tid >> 6;   // 0..3
    const int lane = tid & 63;
    const int hb   = blockIdx.x * HPB;

    __shared__ unsigned short s_list[N_HID];
    __shared__ int4 s_part[4][16];
    __shared__ int  s_fb[HPB];
    __shared__ int  s_n;

    // LIF state: wave 0, lane l <-> neuron hb+l
    int mem = 0, syn = 0, prev_out = 0;
    int in_cur = 0;

    for (int t = 0; t < T_STEPS; ++t) {
        // ---- wave 0: exchange (poll t-1 masks) + build spike list ----
        if (wave == 0) {
            in_cur = (int)in_all[(size_t)t * N_HID + hb + lane]; // hoisted load
            unsigned long long kmask = 0;
            if (t > 0) {
                uint4* rec = pub + (size_t)(t - 1) * NBLK + lane; // lane j <-> block j
                while (__hip_atomic_load((unsigned int*)&rec->z, __ATOMIC_ACQUIRE,
                                         __HIP_MEMORY_SCOPE_AGENT) == 0u)
                    __builtin_amdgcn_s_sleep(1);
                unsigned int lo = __hip_atomic_load((unsigned int*)&rec->x, __ATOMIC_RELAXED,
                                                    __HIP_MEMORY_SCOPE_AGENT);
                unsigned int hi = __hip_atomic_load((unsigned int*)&rec->y, __ATOMIC_RELAXED,
                                                    __HIP_MEMORY_SCOPE_AGENT);
                kmask = (unsigned long long)lo | ((unsigned long long)hi << 32);
            }
            int cnt = __popcll(kmask);
            int inc = cnt;
#pragma unroll
            for (int d = 1; d < 64; d <<= 1) {
                int v = __shfl_up(inc, d);
                if (lane >= d) inc += v;
            }
            int p = inc - cnt;                      // exclusive prefix
            unsigned long long m = kmask;
            while (m) {
                s_list[p++] = (unsigned short)((lane << 6) | __builtin_ctzll(m));
                m &= m - 1;
            }
            if (lane == 63) s_n = inc;              // total spike count
        }
        __syncthreads();                            // list ready for all waves
        const int n = s_n;

        // ---- feedback gather: fb[h] = sum_{k in spikes} v1t[k][h] ----
        int4 acc = {0, 0, 0, 0};
        {
            const int g  = lane >> 4;          // 0..3
            const int li = lane & 15;          // 0..15
            const int wg = (wave << 2) | g;    // 0..15
            const signed char* base = v1t + hb + (li << 2);
#pragma unroll 16
            for (int j = wg; j < n; j += 16) {
                int k = s_list[j];
                int v = *(const int*)(base + (k << 12));
                acc.x += (v << 24) >> 24;
                acc.y += (v << 16) >> 24;
                acc.z += (v << 8)  >> 24;
                acc.w +=  v        >> 24;
            }
        }
#pragma unroll
        for (int mm = 16; mm <= 32; mm <<= 1) {
            acc.x += __shfl_xor(acc.x, mm);
            acc.y += __shfl_xor(acc.y, mm);
            acc.z += __shfl_xor(acc.z, mm);
            acc.w += __shfl_xor(acc.w, mm);
        }
        if (lane < 16) s_part[wave][lane] = acc;
        __syncthreads();

        if (wave == 0 && lane < 16) {
            int4 r;
            r.x = s_part[0][lane].x + s_part[1][lane].x + s_part[2][lane].x + s_part[3][lane].x;
            r.y = s_part[0][lane].y + s_part[1][lane].y + s_part[2][lane].y + s_part[3][lane].y;
            r.z = s_part[0][lane].z + s_part[1][lane].z + s_part[2][lane].z + s_part[3][lane].z;
            r.w = s_part[0][lane].w + s_part[1][lane].w + s_part[2][lane].w + s_part[3][lane].w;
            s_fb[(lane << 2) + 0] = r.x;
            s_fb[(lane << 2) + 1] = r.y;
            s_fb[(lane << 2) + 2] = r.z;
            s_fb[(lane << 2) + 3] = r.w;
        }
        __syncthreads();

        // ---- LIF update + publish (wave 0) ----
        if (wave == 0) {
            int fb = s_fb[lane];
            int syn_curr = in_cur + fb;
            int m  = prev_out ? 0 : mem;             // reset by previous spike
            int out = (m - 1 > 0) ? 1 : 0;           // threshold on reset mem
            mem = (m - (m >> 3)) + syn;              // beta decay + old syn
            syn = (syn - (syn >> 4)) + syn_curr;     // alpha decay + current
            prev_out = out;

            unsigned long long omask = __ballot(out);
            if (lane == 0) {
                uint4* rec = pub + (size_t)t * NBLK + blockIdx.x;
                __hip_atomic_store((unsigned int*)&rec->x, (unsigned int)omask,
                                   __ATOMIC_RELAXED, __HIP_MEMORY_SCOPE_AGENT);
                __hip_atomic_store((unsigned int*)&rec->y, (unsigned int)(omask >> 32),
                                   __ATOMIC_RELAXED, __HIP_MEMORY_SCOPE_AGENT);
                __hip_atomic_store((unsigned int*)&rec->z, 1u,
                                   __ATOMIC_RELEASE, __HIP_MEMORY_SCOPE_AGENT);
            }
        }
        // no trailing barrier: next step's poll is the sync
    }
}

// ---------------------------------------------------------------------------
// ro[t][o] = sum_{k in spikes(t)} w2[o][k]   (spikes decoded from pub masks)
__global__ __launch_bounds__(256) void k_rocur(
    const int* __restrict__ w2,                // [N_OUT][N_HID]
    const uint4* __restrict__ pub,
    int* __restrict__ ro)                      // [T][N_OUT]
{
    const int t = blockIdx.x;
    const int tid = threadIdx.x;
    __shared__ unsigned short s_list[N_HID];
    __shared__ int s_red[32][8];
    __shared__ int s_n;
    if (tid < 64) {
        uint4 rec = pub[(size_t)t * NBLK + tid];
        unsigned long long m = (unsigned long long)rec.x |
                               ((unsigned long long)rec.y << 32);
        int cnt = __popcll(m);
        int inc = cnt;
#pragma unroll
        for (int d = 1; d < 64; d <<= 1) {
            int v = __shfl_up(inc, d);
            if (tid >= d) inc += v;
        }
        int p = inc - cnt;
        while (m) {
            s_list[p++] = (unsigned short)((tid << 6) | __builtin_ctzll(m));
            m &= m - 1;
        }
        if (tid == 63) s_n = inc;
    }
    __syncthreads();
    const int n = s_n;
    const int o = tid >> 3;
    const int r = tid & 7;
    if (o < N_OUT) {
        int acc = 0;
        for (int j = r; j < n; j += 8) acc += w2[(size_t)o * N_HID + s_list[j]];
        s_red[o][r] = acc;
    }
    __syncthreads();
    if (tid < N_OUT) {
        int acc = 0;
#pragma unroll
        for (int q = 0; q < 8; ++q) acc += s_red[tid][q];
        ro[(size_t)t * N_OUT + tid] = acc;
    }
}

// ---------------------------------------------------------------------------
// readout LIF scan (no reset); LDS-staged chunks so the serial loop reads
// LDS (~4 cyc) instead of 1000 dependent global loads. out [N_OUT][T] int32.
#define CH 250
__global__ __launch_bounds__(256) void k_scan(const int* __restrict__ ro,
                                              int* __restrict__ out)
{
    __shared__ int s_ro[CH * N_OUT];   // 20 KB
    const int tid = threadIdx.x;
    int rm = 0, rs = 0;
    for (int c = 0; c < T_STEPS / CH; ++c) {
        __syncthreads();
        for (int i = tid; i < CH * N_OUT; i += 256)
            s_ro[i] = ro[c * CH * N_OUT + i];
        __syncthreads();
        if (tid < N_OUT) {
            for (int j = 0; j < CH; ++j) {
                rm = (rm - (rm >> 3)) + rs;
                rs = (rs - (rs >> 4)) + s_ro[j * N_OUT + tid];
                out[tid * T_STEPS + c * CH + j] = rm;
            }
        }
    }
}

// ---------------------------------------------------------------------------
extern "C" void kernel_launch(void* const* d_in, const int* in_sizes, int n_in,
                              void* d_out, int out_size, void* d_ws, size_t ws_size,
                              hipStream_t stream)
{
    const int* spk = (const int*)d_in[0];   // [1000][700]
    const int* w1  = (const int*)d_in[1];   // [4096][700]
    const int* v1  = (const int*)d_in[2];   // [4096][4096]
    const int* w2  = (const int*)d_in[3];   // [20][4096]
    int* out = (int*)d_out;                 // [20][1000] int32

    char* ws = (char*)d_ws;
    constexpr size_t SZ_PUB   = (size_t)T_STEPS * NBLK * 16;   // 1,024,000
    constexpr size_t OFF_PUB  = 0;
    constexpr size_t OFF_INALL= OFF_PUB + SZ_PUB;              // 8,192,000
    constexpr size_t OFF_V1T  = OFF_INALL + 8192000;           // 16,777,216
    constexpr size_t OFF_W1T  = OFF_V1T + 16777216;            // 2,867,200
    constexpr size_t OFF_RO   = OFF_W1T + 2867200;             // 80,000

    uint4*          pub    = (uint4*)(ws + OFF_PUB);
    short*          in_all = (short*)(ws + OFF_INALL);
    signed char*    v1t    = (signed char*)(ws + OFF_V1T);
    signed char*    w1t    = (signed char*)(ws + OFF_W1T);
    int*            ro     = (int*)(ws + OFF_RO);

    // zero publish flags (required every call: replays reuse the buffer)
    hipMemsetAsync(pub, 0, SZ_PUB, stream);

    dim3 tb(32, 8);
    k_transpose_i8<<<dim3(128, 128), tb, 0, stream>>>(v1, v1t, N_HID, N_HID, N_HID);
    k_transpose_i8<<<dim3(22, 128),  tb, 0, stream>>>(w1, w1t, N_HID, N_IN, N_HID);
    k_inall<<<dim3(16, 63), 256, 0, stream>>>(w1t, spk, in_all);

    k_main<<<dim3(NBLK), dim3(256), 0, stream>>>(in_all, v1t, pub);

    k_rocur<<<dim3(T_STEPS), 256, 0, stream>>>(w2, pub, ro);
    k_scan<<<1, 256, 0, stream>>>(ro, out);
}

// Round 4
// 1753.664 us; speedup vs baseline: 3.2387x; 2.2362x over previous
//
#include <hip/hip_runtime.h>

#define T_STEPS 1000
#define N_IN    700
#define N_HID   4096
#define N_OUT   20
#define NBLK    64
#define HPB     64   // N_HID / NBLK

typedef unsigned int u32x4 __attribute__((ext_vector_type(4)));

// single-transaction 16B device-coherent record ops (one L3 round trip)
__device__ __forceinline__ u32x4 load_rec(const u32x4* p) {
    u32x4 r;
    asm volatile("global_load_dwordx4 %0, %1, off sc0 sc1\n\t"
                 "s_waitcnt vmcnt(0)"
                 : "=v"(r) : "v"(p) : "memory");
    return r;
}
__device__ __forceinline__ void store_rec(u32x4* p, u32x4 v) {
    asm volatile("global_store_dwordx4 %0, %1, off sc0 sc1"
                 :: "v"(p), "v"(v) : "memory");
}

// ---------------------------------------------------------------------------
// w1t[c*4096 + r] = (int8) w1[r*700 + c]   (plain transpose, unbiased)
__global__ __launch_bounds__(256) void k_transpose_i8(
    const int* __restrict__ in, signed char* __restrict__ out,
    int R, int C, int out_stride)
{
    __shared__ signed char tile[32][33];
    const int cx = blockIdx.x * 32;
    const int ry = blockIdx.y * 32;
    const int tx = threadIdx.x;
    const int ty = threadIdx.y;
#pragma unroll
    for (int r = 0; r < 4; ++r) {
        int row = ry + ty + r * 8;
        int col = cx + tx;
        if (row < R && col < C)
            tile[ty + r * 8][tx] = (signed char)in[(size_t)row * C + col];
    }
    __syncthreads();
#pragma unroll
    for (int r = 0; r < 4; ++r) {
        int c   = cx + ty + r * 8;
        int row = ry + tx;
        if (c < C && row < R)
            out[(size_t)c * out_stride + row] = tile[tx][ty + r * 8];
    }
}

// ---------------------------------------------------------------------------
// v1b[(h>>6)*262144 + k*64 + (h&63)] = (uint8)(v1[h][k] + 8)
// block-sliced layout: each k_main block's slice is 256KB -> XCD-L2 resident.
__global__ __launch_bounds__(256) void k_prep_v1(
    const int* __restrict__ in, unsigned char* __restrict__ out)
{
    __shared__ unsigned char tile[32][33];
    const int kx = blockIdx.x * 32;
    const int hy = blockIdx.y * 32;
    const int tx = threadIdx.x;
    const int ty = threadIdx.y;
#pragma unroll
    for (int r = 0; r < 4; ++r) {
        int h = hy + ty + r * 8;
        tile[ty + r * 8][tx] = (unsigned char)(in[(size_t)h * N_HID + kx + tx] + 8);
    }
    __syncthreads();
    const size_t bofs = (size_t)(hy >> 6) * (N_HID * 64) + (hy & 32);
#pragma unroll
    for (int r = 0; r < 4; ++r) {
        int k = kx + ty + r * 8;
        out[bofs + ((size_t)k << 6) + tx] = tile[tx][ty + r * 8];
    }
}

// ---------------------------------------------------------------------------
// in_all[t][h] = sum_i w1t[i][h] * spk[t][i]
__global__ __launch_bounds__(256) void k_inall(
    const signed char* __restrict__ w1t,   // [N_IN][N_HID]
    const int* __restrict__ spk,           // [T][N_IN]
    short* __restrict__ in_all)            // [T][N_HID]
{
    __shared__ int s_spk[16][N_IN];
    const int t0 = blockIdx.y * 16;
    const int tcnt = min(16, T_STEPS - t0);
    const int tid = threadIdx.x;
    for (int b = 0; b < tcnt; ++b)
        for (int i = tid; i < N_IN; i += 256)
            s_spk[b][i] = spk[(size_t)(t0 + b) * N_IN + i];
    __syncthreads();
    const int h = blockIdx.x * 256 + tid;
    int acc[16];
#pragma unroll
    for (int b = 0; b < 16; ++b) acc[b] = 0;
    for (int i = 0; i < N_IN; ++i) {
        int w = (int)w1t[(size_t)i * N_HID + h];
#pragma unroll
        for (int b = 0; b < 16; ++b) acc[b] += w * s_spk[b][i];
    }
    for (int b = 0; b < tcnt; ++b)
        in_all[(size_t)(t0 + b) * N_HID + h] = (short)acc[b];
}

// ---------------------------------------------------------------------------
// Main LIF loop. out(t) depends only on mem(t)/out(t-1), NOT on fb(t):
// publish out(t) at the TOP of step t, then poll step t-1's masks (published
// a full step earlier -> already visible), gather, update syn/mem.
__global__ __launch_bounds__(256) void k_main(
    const short* __restrict__ in_all,          // [T][N_HID]
    const unsigned char* __restrict__ v1b,     // [64][4096][64], biased +8
    u32x4* __restrict__ pub)                   // [T][NBLK], zeroed
{
    const int tid  = threadIdx.x;
    const int wave = tid >> 6;
    const int lane = tid & 63;
    const int hb   = blockIdx.x * HPB;

    __shared__ unsigned short s_list[N_HID];   // 8KB
    __shared__ unsigned int s_part[4][4][8];
    __shared__ int s_n;

    // state (wave 0, lane l <-> neuron hb+l):
    // mt = reset(mem(t), out(t-1)); cur_out = out(t); omask = ballot(out(t))
    int mt = 0, syn = 0, cur_out = 0;
    unsigned long long omask = 0;

    const unsigned char* gbase = v1b + ((size_t)blockIdx.x << 18) + ((lane & 3) << 4);
    const int wg = (wave << 4) | (lane >> 2);  // 0..63, k-subset stride 64

    for (int t = 0; t < T_STEPS; ++t) {
        int in_cur = 0;
        if (wave == 0) {
            if (lane == 0) {
                u32x4 v = { (unsigned)omask, (unsigned)(omask >> 32), 1u, 0u };
                store_rec(pub + (size_t)t * NBLK + blockIdx.x, v);
            }
            in_cur = (int)in_all[(size_t)t * N_HID + hb + lane];
            unsigned long long kmask = 0;
            if (t > 0) {
                const u32x4* rec = pub + (size_t)(t - 1) * NBLK + lane;
                u32x4 r = load_rec(rec);
                while (r.z == 0u) { __builtin_amdgcn_s_sleep(1); r = load_rec(rec); }
                kmask = ((unsigned long long)r.y << 32) | (unsigned long long)r.x;
            }
            int cnt = __popcll(kmask);
            int inc = cnt;
#pragma unroll
            for (int d = 1; d < 64; d <<= 1) {
                int v = __shfl_up(inc, d);
                if (lane >= d) inc += v;
            }
            int p = inc - cnt;                      // exclusive prefix
            unsigned long long m = kmask;
            while (m) {
                s_list[p++] = (unsigned short)((lane << 6) | __builtin_ctzll(m));
                m &= m - 1;
            }
            if (lane == 63) s_n = inc;
        }
        __syncthreads();
        const int n = s_n;

        // gather: 4 lanes x 16B cover one k-row's 64 biased bytes.
        // packed u16-pair accumulation (exact: max 15*4096 < 2^16).
        unsigned int a0=0,a1=0,a2=0,a3=0,a4=0,a5=0,a6=0,a7=0;
#pragma unroll 8
        for (int j = wg; j < n; j += 64) {
            int k = s_list[j];
            u32x4 v = *(const u32x4*)(gbase + ((size_t)k << 6));
            const unsigned int M = 0x00FF00FFu;
            a0 += v.x & M;  a1 += (v.x >> 8) & M;
            a2 += v.y & M;  a3 += (v.y >> 8) & M;
            a4 += v.z & M;  a5 += (v.z >> 8) & M;
            a6 += v.w & M;  a7 += (v.w >> 8) & M;
        }
#pragma unroll
        for (int s = 4; s <= 32; s <<= 1) {
            a0 += __shfl_xor(a0, s); a1 += __shfl_xor(a1, s);
            a2 += __shfl_xor(a2, s); a3 += __shfl_xor(a3, s);
            a4 += __shfl_xor(a4, s); a5 += __shfl_xor(a5, s);
            a6 += __shfl_xor(a6, s); a7 += __shfl_xor(a7, s);
        }
        if (lane < 4) {
            unsigned int* sp = s_part[wave][lane];
            sp[0]=a0; sp[1]=a1; sp[2]=a2; sp[3]=a3;
            sp[4]=a4; sp[5]=a5; sp[6]=a6; sp[7]=a7;
        }
        __syncthreads();

        if (wave == 0) {
            const int li = lane >> 4, b = lane & 15;
            const int c = ((b >> 2) << 1) | (b & 1);
            const int half = (b >> 1) & 1;
            unsigned int s = s_part[0][li][c] + s_part[1][li][c]
                           + s_part[2][li][c] + s_part[3][li][c];
            int fb = (int)((s >> (half << 4)) & 0xFFFFu) - 8 * n;

            // LIF: mem(t+1) = decay3(mt) + syn; syn(t+1) = decay4(syn)+in+fb;
            // mt(t+1) = reset by out(t); out(t+1) = thr(mt(t+1))
            int new_mem = (mt - (mt >> 3)) + syn;
            syn = (syn - (syn >> 4)) + in_cur + fb;
            mt = cur_out ? 0 : new_mem;
            cur_out = (mt - 1 > 0) ? 1 : 0;
            omask = __ballot(cur_out);
        }
    }
}

// ---------------------------------------------------------------------------
// ro[t][o] = sum_{k in spikes(t)} w2[o][k]
__global__ __launch_bounds__(256) void k_rocur(
    const int* __restrict__ w2,                // [N_OUT][N_HID]
    const u32x4* __restrict__ pub,
    int* __restrict__ ro)                      // [T][N_OUT]
{
    const int t = blockIdx.x;
    const int tid = threadIdx.x;
    __shared__ unsigned short s_list[N_HID];
    __shared__ int s_red[32][8];
    __shared__ int s_n;
    if (tid < 64) {
        u32x4 rec = pub[(size_t)t * NBLK + tid];
        unsigned long long m = (unsigned long long)rec.x |
                               ((unsigned long long)rec.y << 32);
        int cnt = __popcll(m);
        int inc = cnt;
#pragma unroll
        for (int d = 1; d < 64; d <<= 1) {
            int v = __shfl_up(inc, d);
            if (tid >= d) inc += v;
        }
        int p = inc - cnt;
        while (m) {
            s_list[p++] = (unsigned short)((tid << 6) | __builtin_ctzll(m));
            m &= m - 1;
        }
        if (tid == 63) s_n = inc;
    }
    __syncthreads();
    const int n = s_n;
    const int o = tid >> 3;
    const int r = tid & 7;
    if (o < N_OUT) {
        int acc = 0;
        for (int j = r; j < n; j += 8) acc += w2[(size_t)o * N_HID + s_list[j]];
        s_red[o][r] = acc;
    }
    __syncthreads();
    if (tid < N_OUT) {
        int acc = 0;
#pragma unroll
        for (int q = 0; q < 8; ++q) acc += s_red[tid][q];
        ro[(size_t)t * N_OUT + tid] = acc;
    }
}

// ---------------------------------------------------------------------------
// readout LIF scan; LDS-staged. out [N_OUT][T] int32.
#define CH 250
__global__ __launch_bounds__(256) void k_scan(const int* __restrict__ ro,
                                              int* __restrict__ out)
{
    __shared__ int s_ro[CH * N_OUT];   // 20 KB
    const int tid = threadIdx.x;
    int rm = 0, rs = 0;
    for (int c = 0; c < T_STEPS / CH; ++c) {
        __syncthreads();
        for (int i = tid; i < CH * N_OUT; i += 256)
            s_ro[i] = ro[c * CH * N_OUT + i];
        __syncthreads();
        if (tid < N_OUT) {
            for (int j = 0; j < CH; ++j) {
                rm = (rm - (rm >> 3)) + rs;
                rs = (rs - (rs >> 4)) + s_ro[j * N_OUT + tid];
                out[tid * T_STEPS + c * CH + j] = rm;
            }
        }
    }
}

// ---------------------------------------------------------------------------
extern "C" void kernel_launch(void* const* d_in, const int* in_sizes, int n_in,
                              void* d_out, int out_size, void* d_ws, size_t ws_size,
                              hipStream_t stream)
{
    const int* spk = (const int*)d_in[0];   // [1000][700]
    const int* w1  = (const int*)d_in[1];   // [4096][700]
    const int* v1  = (const int*)d_in[2];   // [4096][4096]
    const int* w2  = (const int*)d_in[3];   // [20][4096]
    int* out = (int*)d_out;                 // [20][1000] int32

    char* ws = (char*)d_ws;
    constexpr size_t SZ_PUB    = (size_t)T_STEPS * NBLK * 16;   // 1,024,000
    constexpr size_t OFF_PUB   = 0;
    constexpr size_t OFF_INALL = OFF_PUB + SZ_PUB;              // 8,192,000
    constexpr size_t OFF_V1B   = OFF_INALL + 8192000;           // 16,777,216
    constexpr size_t OFF_W1T   = OFF_V1B + 16777216;            // 2,867,200
    constexpr size_t OFF_RO    = OFF_W1T + 2867200;             // 80,000

    u32x4*          pub    = (u32x4*)(ws + OFF_PUB);
    short*          in_all = (short*)(ws + OFF_INALL);
    unsigned char*  v1b    = (unsigned char*)(ws + OFF_V1B);
    signed char*    w1t    = (signed char*)(ws + OFF_W1T);
    int*            ro     = (int*)(ws + OFF_RO);

    hipMemsetAsync(pub, 0, SZ_PUB, stream);   // stale flags from prior replay

    dim3 tb(32, 8);
    k_prep_v1<<<dim3(128, 128), tb, 0, stream>>>(v1, v1b);
    k_transpose_i8<<<dim3(22, 128), tb, 0, stream>>>(w1, w1t, N_HID, N_IN, N_HID);
    k_inall<<<dim3(16, 63), 256, 0, stream>>>(w1t, spk, in_all);

    k_main<<<dim3(NBLK), dim3(256), 0, stream>>>(in_all, v1b, pub);

    k_rocur<<<dim3(T_STEPS), 256, 0, stream>>>(w2, pub, ro);
    k_scan<<<1, 256, 0, stream>>>(ro, out);
}

// Round 6
// 1593.684 us; speedup vs baseline: 3.5638x; 1.1004x over previous
//
#include <hip/hip_runtime.h>

#define T_STEPS 1000
#define N_IN    700
#define N_HID   4096
#define N_OUT   20
#define NBLK    64
#define HPB     64   // N_HID / NBLK

typedef unsigned int u32x4 __attribute__((ext_vector_type(4)));

// synchronous 16B device-coherent load: waitcnt INSIDE the asm block, so the
// destination register is never live-in-flight across compiler-visible code.
__device__ __forceinline__ u32x4 load_rec_sync(const u32x4* p) {
    u32x4 r;
    asm volatile("global_load_dwordx4 %0, %1, off sc0 sc1\n\t"
                 "s_waitcnt vmcnt(0)"
                 : "=v"(r) : "v"(p) : "memory");
    return r;
}
__device__ __forceinline__ void store_rec(u32x4* p, u32x4 v) {
    asm volatile("global_store_dwordx4 %0, %1, off sc0 sc1"
                 :: "v"(p), "v"(v) : "memory");
}

// ---------------------------------------------------------------------------
// w1t[c*4096 + r] = (int8) w1[r*700 + c]
__global__ __launch_bounds__(256) void k_transpose_i8(
    const int* __restrict__ in, signed char* __restrict__ out,
    int R, int C, int out_stride)
{
    __shared__ signed char tile[32][33];
    const int cx = blockIdx.x * 32;
    const int ry = blockIdx.y * 32;
    const int tx = threadIdx.x;
    const int ty = threadIdx.y;
#pragma unroll
    for (int r = 0; r < 4; ++r) {
        int row = ry + ty + r * 8;
        int col = cx + tx;
        if (row < R && col < C)
            tile[ty + r * 8][tx] = (signed char)in[(size_t)row * C + col];
    }
    __syncthreads();
#pragma unroll
    for (int r = 0; r < 4; ++r) {
        int c   = cx + ty + r * 8;
        int row = ry + tx;
        if (c < C && row < R)
            out[(size_t)c * out_stride + row] = tile[tx][ty + r * 8];
    }
}

// ---------------------------------------------------------------------------
// v1b[(h>>6)*262144 + k*64 + (h&63)] = (uint8)(v1[h][k] + 8)
__global__ __launch_bounds__(256) void k_prep_v1(
    const int* __restrict__ in, unsigned char* __restrict__ out)
{
    __shared__ unsigned char tile[32][33];
    const int kx = blockIdx.x * 32;
    const int hy = blockIdx.y * 32;
    const int tx = threadIdx.x;
    const int ty = threadIdx.y;
#pragma unroll
    for (int r = 0; r < 4; ++r) {
        int h = hy + ty + r * 8;
        tile[ty + r * 8][tx] = (unsigned char)(in[(size_t)h * N_HID + kx + tx] + 8);
    }
    __syncthreads();
    const size_t bofs = (size_t)(hy >> 6) * (N_HID * 64) + (hy & 32);
#pragma unroll
    for (int r = 0; r < 4; ++r) {
        int k = kx + ty + r * 8;
        out[bofs + ((size_t)k << 6) + tx] = tile[tx][ty + r * 8];
    }
}

// ---------------------------------------------------------------------------
// in_all2 block-major: in_all2[(h>>6)*T*64 + t*64 + (h&63)]
__global__ __launch_bounds__(256) void k_inall(
    const signed char* __restrict__ w1t,   // [N_IN][N_HID]
    const int* __restrict__ spk,           // [T][N_IN]
    short* __restrict__ in_all2)           // [NBLK][T][64]
{
    __shared__ int s_spk[16][N_IN];
    const int t0 = blockIdx.y * 16;
    const int tcnt = min(16, T_STEPS - t0);
    const int tid = threadIdx.x;
    for (int b = 0; b < tcnt; ++b)
        for (int i = tid; i < N_IN; i += 256)
            s_spk[b][i] = spk[(size_t)(t0 + b) * N_IN + i];
    __syncthreads();
    const int h = blockIdx.x * 256 + tid;
    int acc[16];
#pragma unroll
    for (int b = 0; b < 16; ++b) acc[b] = 0;
    for (int i = 0; i < N_IN; ++i) {
        int w = (int)w1t[(size_t)i * N_HID + h];
#pragma unroll
        for (int b = 0; b < 16; ++b) acc[b] += w * s_spk[b][i];
    }
    const size_t base = (size_t)(h >> 6) * (T_STEPS * 64) + (h & 63);
    for (int b = 0; b < tcnt; ++b)
        in_all2[base + (size_t)(t0 + b) * 64] = (short)acc[b];
}

// ---------------------------------------------------------------------------
// Main LIF loop. Slot semantics: pub[r] = mask(out(r)), flag in .z.
//   top of iter t: compute out(t+1) from {mm=m'(t), synv=syn(t-1), out_t};
//                  publish pub[t+1]  (so pub[r] lands 1.5 iters before use)
//   consume pub[t-1] from LDS (prefetched at iter t-1 via global_load_lds;
//                  vmcnt drained at that iter's barrier); flag=0 -> sync retry
//   prefetch pub[t] into the other LDS buffer (compiler-tracked async)
//   gather fb over wave-private sublists; one __syncthreads per step.
// Records are write-once and replay-deterministic: any cached copy with
// flag=1 is bit-correct, so cache staleness can only cause a (safe) retry.
__global__ __launch_bounds__(256) void k_main(
    const short* __restrict__ in_all2,         // [NBLK][T][64]
    const unsigned char* __restrict__ v1b,     // [64][4096][64], biased +8
    u32x4* __restrict__ pub)                   // [T+1][NBLK], flags zeroed
{
    const int tid  = threadIdx.x;
    const int wave = tid >> 6;
    const int lane = tid & 63;
    const int bid  = blockIdx.x;

    __shared__ unsigned short s_list[4][1024];     // wave-private sublists, 8KB
    __shared__ u32x4 s_rec[2][NBLK];               // prefetched records, 2KB
    __shared__ unsigned int s_part[2][4][4][8];    // 1KB
    __shared__ int s_nw[2][4];

    // wave-0 lookahead state: mm = m'(t), synv = syn(t-1), out_t = out(t)
    int mm = 0, synv = 0, out_t = 0;

    const unsigned char* gbase = v1b + ((size_t)bid << 18) + ((lane & 3) << 4);
    const int slot    = lane >> 2;                 // k-slot within wave (0..15)
    const int mb      = (wave << 4) | slot;        // mask-block this lane decodes
    const int frag_sh = (lane & 3) << 4;           // 16-bit fragment shift
    const int kbase   = (mb << 6) + frag_sh;
    const short* in_base = in_all2 + (size_t)bid * (T_STEPS * 64) + lane;

    if (tid == 0) { u32x4 v = {0u, 0u, 1u, 0u}; store_rec(pub + bid, v); }
    __syncthreads();

    for (int t = 0; t < T_STEPS; ++t) {
        const int cur = t & 1;
        int in_cur = 0;
        if (wave == 0) {
            // mem(t) = decay3(m'(t)) + syn(t-1);  out(t+1) = thr(reset(mem(t), out(t)))
            int mem_t = (mm - (mm >> 3)) + synv;
            int mnext = out_t ? 0 : mem_t;
            int out_n = (mnext - 1 > 0) ? 1 : 0;
            unsigned long long om = __ballot(out_n);
            if (lane == 0) {
                u32x4 v = {(unsigned)om, (unsigned)(om >> 32), 1u, 0u};
                store_rec(pub + (size_t)(t + 1) * NBLK + bid, v);
            }
            in_cur = (int)in_base[t * 64];
            mm = mnext; out_t = out_n;
        }

        // ---- consume row t-1; build wave-private sublist (16 masks/wave) ----
        unsigned int frag = 0;
        if (t > 0) {
            u32x4 rec = s_rec[cur][mb];
            if (rec.z == 0u) {                      // rare: not yet published
                const u32x4* rp = pub + (size_t)(t - 1) * NBLK + mb;
                do { __builtin_amdgcn_s_sleep(1); rec = load_rec_sync(rp); }
                while (rec.z == 0u);
            }
            unsigned long long km = ((unsigned long long)rec.y << 32) |
                                     (unsigned long long)rec.x;
            frag = (unsigned int)((km >> frag_sh) & 0xFFFFull);
        }
        int cnt = __popc(frag);
        int inc = cnt;
#pragma unroll
        for (int d = 1; d < 64; d <<= 1) {
            int v = __shfl_up(inc, d);
            if (lane >= d) inc += v;
        }
        int p = inc - cnt;
        unsigned int m = frag;
        while (m) {
            s_list[wave][p++] = (unsigned short)(kbase + __builtin_ctz(m));
            m &= m - 1;
        }
        const int n_w = __shfl(inc, 63);
        if (lane == 0) s_nw[cur][wave] = n_w;

        // ---- prefetch row t into the other LDS buffer (compiler-tracked) ----
        if (wave == 0)
            __builtin_amdgcn_global_load_lds(
                (const void*)(pub + (size_t)t * NBLK + lane),
                (void*)&s_rec[cur ^ 1][0], 16, 0, /*sc0|sc1*/ 17);

        // own-wave ds_writes must be visible to own-wave ds_reads
        asm volatile("s_waitcnt lgkmcnt(0)" ::: "memory");

        // ---- gather: 4 lanes x 16B per k-row, over own sublist ----
        unsigned int a0=0,a1=0,a2=0,a3=0,a4=0,a5=0,a6=0,a7=0;
#pragma unroll 8
        for (int j = slot; j < n_w; j += 16) {
            int k = s_list[wave][j];
            u32x4 v = *(const u32x4*)(gbase + ((size_t)k << 6));
            const unsigned int M = 0x00FF00FFu;
            a0 += v.x & M;  a1 += (v.x >> 8) & M;
            a2 += v.y & M;  a3 += (v.y >> 8) & M;
            a4 += v.z & M;  a5 += (v.z >> 8) & M;
            a6 += v.w & M;  a7 += (v.w >> 8) & M;
        }
#pragma unroll
        for (int s = 4; s <= 32; s <<= 1) {
            a0 += __shfl_xor(a0, s); a1 += __shfl_xor(a1, s);
            a2 += __shfl_xor(a2, s); a3 += __shfl_xor(a3, s);
            a4 += __shfl_xor(a4, s); a5 += __shfl_xor(a5, s);
            a6 += __shfl_xor(a6, s); a7 += __shfl_xor(a7, s);
        }
        if (lane < 4) {
            unsigned int* sp = s_part[cur][wave][lane];
            sp[0]=a0; sp[1]=a1; sp[2]=a2; sp[3]=a3;
            sp[4]=a4; sp[5]=a5; sp[6]=a6; sp[7]=a7;
        }
        __syncthreads();   // publishes s_part/s_nw; drains wave0's load_lds

        // ---- wave 0: final sum + syn update ----
        if (wave == 0) {
            const int n = s_nw[cur][0] + s_nw[cur][1] + s_nw[cur][2] + s_nw[cur][3];
            const int li = lane >> 4, b = lane & 15;
            const int c = ((b >> 2) << 1) | (b & 1);
            const int half = (b >> 1) & 1;
            unsigned int s = s_part[cur][0][li][c] + s_part[cur][1][li][c]
                           + s_part[cur][2][li][c] + s_part[cur][3][li][c];
            int fb = (int)((s >> (half << 4)) & 0xFFFFu) - 8 * n;
            synv = (synv - (synv >> 4)) + in_cur + fb;     // syn(t)
        }
    }
}

// ---------------------------------------------------------------------------
// ro[t][o] = sum_{k in spikes(t)} w2[o][k]; pub[t] = mask(out(t))
__global__ __launch_bounds__(256) void k_rocur(
    const int* __restrict__ w2,                // [N_OUT][N_HID]
    const u32x4* __restrict__ pub,
    int* __restrict__ ro)                      // [T][N_OUT]
{
    const int t = blockIdx.x;
    const int tid = threadIdx.x;
    __shared__ unsigned short s_list[N_HID];
    __shared__ int s_red[32][8];
    __shared__ int s_n;
    if (tid < 64) {
        u32x4 rec = pub[(size_t)t * NBLK + tid];
        unsigned long long m = (unsigned long long)rec.x |
                               ((unsigned long long)rec.y << 32);
        int cnt = __popcll(m);
        int inc = cnt;
#pragma unroll
        for (int d = 1; d < 64; d <<= 1) {
            int v = __shfl_up(inc, d);
            if (tid >= d) inc += v;
        }
        int p = inc - cnt;
        while (m) {
            s_list[p++] = (unsigned short)((tid << 6) | __builtin_ctzll(m));
            m &= m - 1;
        }
        if (tid == 63) s_n = inc;
    }
    __syncthreads();
    const int n = s_n;
    const int o = tid >> 3;
    const int r = tid & 7;
    if (o < N_OUT) {
        int acc = 0;
        for (int j = r; j < n; j += 8) acc += w2[(size_t)o * N_HID + s_list[j]];
        s_red[o][r] = acc;
    }
    __syncthreads();
    if (tid < N_OUT) {
        int acc = 0;
#pragma unroll
        for (int q = 0; q < 8; ++q) acc += s_red[tid][q];
        ro[(size_t)t * N_OUT + tid] = acc;
    }
}

// ---------------------------------------------------------------------------
// readout LIF scan; LDS-staged reads + coalesced stores. out [N_OUT][T] int32.
#define CH 250
__global__ __launch_bounds__(256) void k_scan(const int* __restrict__ ro,
                                              int* __restrict__ out)
{
    __shared__ int s_ro[CH * N_OUT];    // 20 KB
    __shared__ int s_out[CH * N_OUT];   // 20 KB
    const int tid = threadIdx.x;
    int rm = 0, rs = 0;
    for (int c = 0; c < T_STEPS / CH; ++c) {
        for (int i = tid; i < CH * N_OUT; i += 256)
            s_ro[i] = ro[c * CH * N_OUT + i];
        __syncthreads();
        if (tid < N_OUT) {
            for (int j = 0; j < CH; ++j) {
                rm = (rm - (rm >> 3)) + rs;
                rs = (rs - (rs >> 4)) + s_ro[j * N_OUT + tid];
                s_out[j * N_OUT + tid] = rm;
            }
        }
        __syncthreads();
        for (int i = tid; i < CH * N_OUT; i += 256) {
            int o = i / CH, j = i - o * CH;
            out[o * T_STEPS + c * CH + j] = s_out[j * N_OUT + o];
        }
        __syncthreads();
    }
}

// ---------------------------------------------------------------------------
extern "C" void kernel_launch(void* const* d_in, const int* in_sizes, int n_in,
                              void* d_out, int out_size, void* d_ws, size_t ws_size,
                              hipStream_t stream)
{
    const int* spk = (const int*)d_in[0];   // [1000][700]
    const int* w1  = (const int*)d_in[1];   // [4096][700]
    const int* v1  = (const int*)d_in[2];   // [4096][4096]
    const int* w2  = (const int*)d_in[3];   // [20][4096]
    int* out = (int*)d_out;                 // [20][1000] int32

    char* ws = (char*)d_ws;
    constexpr size_t SZ_PUB    = (size_t)(T_STEPS + 1) * NBLK * 16; // 1,025,024
    constexpr size_t OFF_PUB   = 0;
    constexpr size_t OFF_INALL = OFF_PUB + SZ_PUB;
    constexpr size_t OFF_V1B   = OFF_INALL + 8192000;
    constexpr size_t OFF_W1T   = OFF_V1B + 16777216;
    constexpr size_t OFF_RO    = OFF_W1T + 2867200;

    u32x4*          pub    = (u32x4*)(ws + OFF_PUB);
    short*          in_all = (short*)(ws + OFF_INALL);
    unsigned char*  v1b    = (unsigned char*)(ws + OFF_V1B);
    signed char*    w1t    = (signed char*)(ws + OFF_W1T);
    int*            ro     = (int*)(ws + OFF_RO);

    hipMemsetAsync(pub, 0, SZ_PUB, stream);   // clear flags (graph replays)

    dim3 tb(32, 8);
    k_prep_v1<<<dim3(128, 128), tb, 0, stream>>>(v1, v1b);
    k_transpose_i8<<<dim3(22, 128), tb, 0, stream>>>(w1, w1t, N_HID, N_IN, N_HID);
    k_inall<<<dim3(16, 63), 256, 0, stream>>>(w1t, spk, in_all);

    k_main<<<dim3(NBLK), dim3(256), 0, stream>>>(in_all, v1b, pub);

    k_rocur<<<dim3(T_STEPS), 256, 0, stream>>>(w2, pub, ro);
    k_scan<<<1, 256, 0, stream>>>(ro, out);
}